// Round 13
// baseline (226.861 us; speedup 1.0000x reference)
//
#include <hip/hip_runtime.h>
#include <hip/hip_bf16.h>

#define N_NODES 20000
#define N_EDGES 640000
#define HIDDEN 256
#define HEADS 8
#define HEAD_DIM 32
#define N_FEATS 9
#define VOCAB 119

typedef __hip_bfloat16 bf16;
typedef __attribute__((ext_vector_type(8))) short short8;
typedef __attribute__((ext_vector_type(4))) float f32x4;

__device__ __forceinline__ ushort f2u(float x) { union { ushort u; bf16 b; } c; c.b = __float2bfloat16(x); return c.u; }
__device__ __forceinline__ void unpack8(uint4 u, float* f) {
    f[0] = __uint_as_float(u.x << 16); f[1] = __uint_as_float(u.x & 0xffff0000u);
    f[2] = __uint_as_float(u.y << 16); f[3] = __uint_as_float(u.y & 0xffff0000u);
    f[4] = __uint_as_float(u.z << 16); f[5] = __uint_as_float(u.z & 0xffff0000u);
    f[6] = __uint_as_float(u.w << 16); f[7] = __uint_as_float(u.w & 0xffff0000u);
}
__device__ __forceinline__ uint pack2(float a, float b) {
    union { __hip_bfloat162 h; uint u; } c;
    c.h = __float22bfloat162_rn(make_float2(a, b));
    return c.u;
}

// 2-way bf16 dot with f32 accumulate: 1 VALU instr, operands already packed.
#if __has_builtin(__builtin_amdgcn_fdot2_f32_bf16)
typedef __attribute__((ext_vector_type(2))) __bf16 bf16x2_t;
__device__ __forceinline__ float dot2bf(uint a, uint b, float c) {
    return __builtin_amdgcn_fdot2_f32_bf16(__builtin_bit_cast(bf16x2_t, a),
                                           __builtin_bit_cast(bf16x2_t, b), c, false);
}
#else
__device__ __forceinline__ float dot2bf(uint a, uint b, float c) {
    return c + __uint_as_float(a << 16) * __uint_as_float(b << 16)
             + __uint_as_float(a & 0xffff0000u) * __uint_as_float(b & 0xffff0000u);
}
#endif

// ---------------------------------------------------------------- fused pre-work
// blocks [0,5000): encode  (h[n][t] = sum_f emb[f][X[n,f]][t], bf16 out)
// blocks [5000,6027): weight fp32->bf16 (concat qkv) + bias concat
// blocks [6027,6106): row_ptr by binary search
__global__ void k_pre(const int* __restrict__ X, const float* __restrict__ emb,
                      bf16* __restrict__ h,
                      const float* __restrict__ qw, const float* __restrict__ kw,
                      const float* __restrict__ vw, const float* __restrict__ ow,
                      const float* __restrict__ qb, const float* __restrict__ kb,
                      const float* __restrict__ vb,
                      bf16* __restrict__ wqkv, bf16* __restrict__ wo,
                      float* __restrict__ qkvb,
                      const int* __restrict__ erow, int* __restrict__ row_ptr) {
    int b = blockIdx.x;
    if (b < 5000) {
        int tid = b * 256 + threadIdx.x;
        int n = tid >> 6;
        int c4 = (tid & 63) * 4;
        float4 a = make_float4(0.f, 0.f, 0.f, 0.f);
#pragma unroll
        for (int f = 0; f < N_FEATS; ++f) {
            int idx = X[n * N_FEATS + f];
            float4 e = *(const float4*)(emb + ((size_t)(f * VOCAB + idx)) * HIDDEN + c4);
            a.x += e.x; a.y += e.y; a.z += e.z; a.w += e.w;
        }
        ushort4 o = make_ushort4(f2u(a.x), f2u(a.y), f2u(a.z), f2u(a.w));
        *(ushort4*)((ushort*)h + (size_t)n * HIDDEN + c4) = o;
    } else if (b < 6027) {
        int i = (b - 5000) * 256 + threadIdx.x;     // 262912 total
        if (i < 196608) {
            const float* s = i < 65536 ? qw : i < 131072 ? kw : vw;
            wqkv[i] = __float2bfloat16(s[i & 65535]);
        } else if (i < 262144) {
            wo[i - 196608] = __float2bfloat16(ow[i - 196608]);
        } else if (i < 262912) {
            int j = i - 262144;                      // 768 bias elems
            const float* s = j < 256 ? qb : j < 512 ? kb : vb;
            qkvb[j] = s[j & 255];
        }
    } else {
        int n = (b - 6027) * 256 + threadIdx.x;
        if (n > N_NODES) return;
        int lo = 0, hi = N_EDGES;
        while (lo < hi) {
            int mid = (lo + hi) >> 1;
            if (erow[mid] < n) lo = mid + 1; else hi = mid;
        }
        row_ptr[n] = lo;
    }
}

// ---------------------------------------------------------------- MFMA GEMM core
// (R10 structure: LDS-staged A+B, register prefetch, 2 barriers/K-iter.)
// MODE 0: qkv -> head-pair-sliced layouts  qhp[hp][n][64], kvhp[hp][n][128]
// MODE 1: float out [n][256]
// GUARD: per-element n bounds checks (only the last x-block needs them)
// TM: row-tile (128 or 64). Cols always 128.
template <int MODE, bool GUARD, int TM>
__device__ __forceinline__ void gemm_core(const bf16* __restrict__ A,
                                          const bf16* __restrict__ W,
                                          const float* __restrict__ bias,
                                          void* __restrict__ Y0, void* __restrict__ Y1,
                                          float s_q, int n0, int d0) {
    constexpr int RI = TM / 32;          // row subtiles per wave (4 or 2)
    __shared__ short As[TM * 72];
    __shared__ short Bs[128 * 72];
    int t = threadIdx.x;
    int lane = t & 63, w = t >> 6;
    int wr = (w >> 1) * (TM / 2), wc = (w & 1) * 64;
    int lr = lane & 15, quad = lane >> 4;

    f32x4 acc[RI][4] = {};
    short8 ra[RI], rb[4];
    int srowA[RI], skoA[RI], srowB[4], skoB[4];
#pragma unroll
    for (int it = 0; it < RI; ++it) { int c = t + 256 * it; srowA[it] = c >> 3; skoA[it] = (c & 7) * 8; }
#pragma unroll
    for (int it = 0; it < 4; ++it) { int c = t + 256 * it; srowB[it] = c >> 3; skoB[it] = (c & 7) * 8; }

    // prologue: load k0=0, stage to LDS
#pragma unroll
    for (int it = 0; it < RI; ++it) {
        int n = n0 + srowA[it];
        short8 av = {};
        if (!GUARD || n < N_NODES) av = *(const short8*)(A + (size_t)n * HIDDEN + skoA[it]);
        ra[it] = av;
    }
#pragma unroll
    for (int it = 0; it < 4; ++it)
        rb[it] = *(const short8*)(W + (size_t)(d0 + srowB[it]) * HIDDEN + skoB[it]);
#pragma unroll
    for (int it = 0; it < RI; ++it) *(short8*)(&As[srowA[it] * 72 + skoA[it]]) = ra[it];
#pragma unroll
    for (int it = 0; it < 4; ++it)  *(short8*)(&Bs[srowB[it] * 72 + skoB[it]]) = rb[it];
    __syncthreads();

    for (int k0 = 64; k0 < 256; k0 += 64) {
        // prefetch next K-slab into regs (overlaps with MFMA below)
#pragma unroll
        for (int it = 0; it < RI; ++it) {
            int n = n0 + srowA[it];
            short8 av = {};
            if (!GUARD || n < N_NODES) av = *(const short8*)(A + (size_t)n * HIDDEN + k0 + skoA[it]);
            ra[it] = av;
        }
#pragma unroll
        for (int it = 0; it < 4; ++it)
            rb[it] = *(const short8*)(W + (size_t)(d0 + srowB[it]) * HIDDEN + k0 + skoB[it]);
        {
            short8 af[RI][2], bfr[4][2];
#pragma unroll
            for (int i = 0; i < RI; ++i)
#pragma unroll
                for (int kk = 0; kk < 2; ++kk)
                    af[i][kk] = *(short8*)(&As[(wr + i * 16 + lr) * 72 + kk * 32 + quad * 8]);
#pragma unroll
            for (int j = 0; j < 4; ++j)
#pragma unroll
                for (int kk = 0; kk < 2; ++kk)
                    bfr[j][kk] = *(short8*)(&Bs[(wc + j * 16 + lr) * 72 + kk * 32 + quad * 8]);
#pragma unroll
            for (int kk = 0; kk < 2; ++kk)
#pragma unroll
                for (int i = 0; i < RI; ++i)
#pragma unroll
                    for (int j = 0; j < 4; ++j)
                        acc[i][j] = __builtin_amdgcn_mfma_f32_16x16x32_bf16(
                            af[i][kk], bfr[j][kk], acc[i][j], 0, 0, 0);
        }
        __syncthreads();
#pragma unroll
        for (int it = 0; it < RI; ++it) *(short8*)(&As[srowA[it] * 72 + skoA[it]]) = ra[it];
#pragma unroll
        for (int it = 0; it < 4; ++it)  *(short8*)(&Bs[srowB[it] * 72 + skoB[it]]) = rb[it];
        __syncthreads();
    }
    // last compute
    {
        short8 af[RI][2], bfr[4][2];
#pragma unroll
        for (int i = 0; i < RI; ++i)
#pragma unroll
            for (int kk = 0; kk < 2; ++kk)
                af[i][kk] = *(short8*)(&As[(wr + i * 16 + lr) * 72 + kk * 32 + quad * 8]);
#pragma unroll
        for (int j = 0; j < 4; ++j)
#pragma unroll
            for (int kk = 0; kk < 2; ++kk)
                bfr[j][kk] = *(short8*)(&Bs[(wc + j * 16 + lr) * 72 + kk * 32 + quad * 8]);
#pragma unroll
        for (int kk = 0; kk < 2; ++kk)
#pragma unroll
            for (int i = 0; i < RI; ++i)
#pragma unroll
                for (int j = 0; j < 4; ++j)
                    acc[i][j] = __builtin_amdgcn_mfma_f32_16x16x32_bf16(
                        af[i][kk], bfr[j][kk], acc[i][j], 0, 0, 0);
    }

    // epilogue: C/D layout col=lane&15, row=quad*4+reg
    // target selection is UNIFORM per j (dbase has no lane term) -> scalar branches
#pragma unroll
    for (int j = 0; j < 4; ++j) {
        int dbase = d0 + wc + j * 16;          // uniform
        float bj = bias[dbase + lr];
        if constexpr (MODE == 0) {
            float sc = (dbase < 256) ? s_q : 1.f;
            ushort* dst; int stride;
            if (dbase < 256) {
                dst = (ushort*)Y0 + (size_t)(dbase >> 6) * N_NODES * 64 + (dbase & 63) + lr;
                stride = 64;
            } else if (dbase < 512) {
                int e = dbase - 256;
                dst = (ushort*)Y1 + (size_t)(e >> 6) * N_NODES * 128 + (e & 63) + lr;
                stride = 128;
            } else {
                int e = dbase - 512;
                dst = (ushort*)Y1 + (size_t)(e >> 6) * N_NODES * 128 + 64 + (e & 63) + lr;
                stride = 128;
            }
#pragma unroll
            for (int i = 0; i < RI; ++i)
#pragma unroll
                for (int r = 0; r < 4; ++r) {
                    int n = n0 + wr + i * 16 + quad * 4 + r;
                    if (GUARD && n >= N_NODES) continue;
                    dst[(size_t)n * stride] = f2u((acc[i][j][r] + bj) * sc);
                }
        } else {
            float* dst = (float*)Y0 + dbase + lr;
#pragma unroll
            for (int i = 0; i < RI; ++i)
#pragma unroll
                for (int r = 0; r < 4; ++r) {
                    int n = n0 + wr + i * 16 + quad * 4 + r;
                    if (GUARD && n >= N_NODES) continue;
                    dst[(size_t)n * HIDDEN] = acc[i][j][r] + bj;
                }
        }
    }
}

__global__ __launch_bounds__(256, 2) void k_gemm_qkv(
    const bf16* __restrict__ A, const bf16* __restrict__ wqkv,
    const float* __restrict__ qkvb, ushort* __restrict__ qhp,
    ushort* __restrict__ kvhp, float qscale) {
    int n0 = blockIdx.x * 128;
    if (n0 + 128 <= N_NODES)
        gemm_core<0, false, 128>(A, wqkv, qkvb, qhp, kvhp, qscale, n0, blockIdx.y * 128);
    else
        gemm_core<0, true, 128>(A, wqkv, qkvb, qhp, kvhp, qscale, n0, blockIdx.y * 128);
}

// TM=64: 626 blocks (2.4/CU), 27 KB LDS, 4 blocks/CU occupancy target
__global__ __launch_bounds__(256, 4) void k_gemm_o(
    const bf16* __restrict__ A, const bf16* __restrict__ W,
    const float* __restrict__ bias, float* __restrict__ Y) {
    int n0 = blockIdx.x * 64;
    if (n0 + 64 <= N_NODES)
        gemm_core<1, false, 64>(A, W, bias, Y, nullptr, 1.f, n0, blockIdx.y * 128);
    else
        gemm_core<1, true, 64>(A, W, bias, Y, nullptr, 1.f, n0, blockIdx.y * 128);
}

// ---------------------------------------------------------------- fused attention
// Head-pair partitioned (XCD-local kv) + zero-waste lanes + packed bf16 dot +
// EXPLICIT distance-2 software pipeline (x unroll 2 -> 8 gathers in flight).
// wave = (node, hp); lane = slot*8 + d8 (slot = lane>>3, head = d8>>2).
// Fast path deg<=64: cols live in c_all lane-space; OOB slots wrap via &63 to
// a valid col of the same node and are p-masked -> no clamps, no branches.
// Slow path deg>64 (rare): old clamped loop.
__global__ __launch_bounds__(256) void k_attn(
    const int* __restrict__ row_ptr, const int* __restrict__ col,
    const ushort* __restrict__ qhp, const ushort* __restrict__ kvhp,
    bf16* __restrict__ agg) {
    int b = blockIdx.x;
    int x = b & 7;
    int hp = x & 3;
    int wave = threadIdx.x >> 6;
    int n = (b >> 3) * 8 + (x >> 2) * 4 + wave;
    int lane = threadIdx.x & 63;
    int my = lane >> 3;          // edge slot 0..7
    int d8 = lane & 7;           // dim slot (head = d8>>2)

    int start = row_ptr[n];
    int deg = row_ptr[n + 1] - start;

    ushort* orow = (ushort*)agg + (size_t)n * HIDDEN + hp * 64 + d8 * 8;
    if (deg == 0) {
        if (lane < 8) { uint4 zo = {}; *(uint4*)orow = zo; }
        return;
    }

    const ushort* qrow = qhp + ((size_t)hp * N_NODES + n) * 64;
    uint4 qu = *(const uint4*)(qrow + d8 * 8);   // packed bf16 pairs, no unpack

    const ushort* kvbase = kvhp + (size_t)hp * N_NODES * 128;
    const int* cb = col + start;

    float z = 0.f;
    float av[8] = {};

    if (deg <= 64) {                      // deg ~ Poisson(32): nearly always
        int c_all = cb[min(lane, deg - 1)];
        uint4 kbuf[2], vbuf[2];
        {
            int c0 = __shfl(c_all, my);
            int c1 = __shfl(c_all, (8 + my) & 63);
            const ushort* p0 = kvbase + (((uint)c0 << 7) + (uint)d8 * 8);
            const ushort* p1 = kvbase + (((uint)c1 << 7) + (uint)d8 * 8);
            kbuf[0] = *(const uint4*)(p0); vbuf[0] = *(const uint4*)(p0 + 64);
            kbuf[1] = *(const uint4*)(p1); vbuf[1] = *(const uint4*)(p1 + 64);
        }
        int nb = (deg + 7) >> 3;
#pragma unroll 2
        for (int it = 0; it < nb; ++it) {
            // prefetch it+2 (wrapped -> always-valid col, masked later)
            int cn = __shfl(c_all, ((it + 2) * 8 + my) & 63);
            const ushort* pn = kvbase + (((uint)cn << 7) + (uint)d8 * 8);
            uint4 kn = *(const uint4*)(pn);
            uint4 vn = *(const uint4*)(pn + 64);

            uint4 ku = kbuf[it & 1], vu = vbuf[it & 1];
            float sa = dot2bf(ku.x, qu.x, 0.f);
            float sb = dot2bf(ku.y, qu.y, 0.f);
            sa = dot2bf(ku.z, qu.z, sa);
            sb = dot2bf(ku.w, qu.w, sb);
            float s = sa + sb;
            s += __shfl_xor(s, 1);
            s += __shfl_xor(s, 2);       // lane holds its (edge, head) score

            float p = (it * 8 + my < deg) ? __expf(s) : 0.f;
            z += p;
            float vf[8];
            unpack8(vu, vf);
#pragma unroll
            for (int d = 0; d < 8; ++d) av[d] += p * vf[d];

            kbuf[it & 1] = kn; vbuf[it & 1] = vn;
        }
    } else {
        for (int i = 0; i < deg; i += 8) {
            int idx = i + my;
            int cidx = idx < deg ? idx : deg - 1;
            int c = cb[cidx];
            const ushort* kp = kvbase + (((uint)c << 7) + (uint)d8 * 8);
            uint4 ku = *(const uint4*)(kp);
            uint4 vu = *(const uint4*)(kp + 64);
            float s = dot2bf(ku.x, qu.x, 0.f);
            s = dot2bf(ku.y, qu.y, s);
            s = dot2bf(ku.z, qu.z, s);
            s = dot2bf(ku.w, qu.w, s);
            s += __shfl_xor(s, 1);
            s += __shfl_xor(s, 2);
            float p = (idx < deg) ? __expf(s) : 0.f;
            z += p;
            float vf[8];
            unpack8(vu, vf);
#pragma unroll
            for (int d = 0; d < 8; ++d) av[d] += p * vf[d];
        }
    }

    // combine the 8 edge slots: orbits preserve d8 (dims/heads stay separate)
    z += __shfl_xor(z, 8); z += __shfl_xor(z, 16); z += __shfl_xor(z, 32);
#pragma unroll
    for (int d = 0; d < 8; ++d) {
        av[d] += __shfl_xor(av[d], 8);
        av[d] += __shfl_xor(av[d], 16);
        av[d] += __shfl_xor(av[d], 32);
    }

    if (lane < 8) {                      // slot-0 lanes hold the totals
        float invz = 1.f / z;
        uint4 o;
        o.x = pack2(av[0] * invz, av[1] * invz);
        o.y = pack2(av[2] * invz, av[3] * invz);
        o.z = pack2(av[4] * invz, av[5] * invz);
        o.w = pack2(av[6] * invz, av[7] * invz);
        *(uint4*)orow = o;
    }
}

// ---------------------------------------------------------------- launch
extern "C" void kernel_launch(void* const* d_in, const int* in_sizes, int n_in,
                              void* d_out, int out_size, void* d_ws, size_t ws_size,
                              hipStream_t stream) {
    const int*   X    = (const int*)d_in[0];
    const int*   erow = (const int*)d_in[1];
    const int*   ecol = (const int*)d_in[2];
    const float* emb  = (const float*)d_in[3];
    const float* q_w  = (const float*)d_in[4];
    const float* q_b  = (const float*)d_in[5];
    const float* k_w  = (const float*)d_in[6];
    const float* k_b  = (const float*)d_in[7];
    const float* v_w  = (const float*)d_in[8];
    const float* v_b  = (const float*)d_in[9];
    const float* o_w  = (const float*)d_in[10];
    const float* o_b  = (const float*)d_in[11];
    float* out = (float*)d_out;

    char* ws = (char*)d_ws;
    // layout (bytes):
    //   h / agg (aliased) : bf16 N*256       = 10,240,000  @ 0
    //   qhp               : bf16 4*N*64      = 10,240,000  @ 10,240,000
    //   kvhp              : bf16 4*N*128     = 20,480,000  @ 20,480,000
    //   wqkv              : bf16 768*256     =    393,216  @ 40,960,000
    //   wo                : bf16 256*256     =    131,072  @ 41,353,216
    //   qkvb              : fp32 768         =      3,072  @ 41,484,288
    //   row_ptr           : int (N+1)        =     80,004  @ 41,487,360
    bf16*   h    = (bf16*)(ws);
    bf16*   agg  = (bf16*)(ws);                 // aliases h (dead after QKV GEMM)
    ushort* qhp  = (ushort*)(ws + 10240000);
    ushort* kvhp = (ushort*)(ws + 20480000);
    bf16*   wqkv = (bf16*)(ws + 40960000);
    bf16*   wo   = (bf16*)(ws + 41353216);
    float*  qkvb = (float*)(ws + 41484288);
    int* row_ptr = (int*)(ws + 41487360);

    // fused pre-work: encode (5000) + weight prep (1027) + row_ptr (79)
    k_pre<<<6106, 256, 0, stream>>>(X, emb, h, q_w, k_w, v_w, o_w,
                                    q_b, k_b, v_b, wqkv, wo, qkvb, erow, row_ptr);

    const float qscale = 0.17677669529663687f;  // 1/sqrt(32)
    dim3 gqkv((N_NODES + 127) / 128, 768 / 128);
    k_gemm_qkv<<<gqkv, 256, 0, stream>>>(h, wqkv, qkvb, qhp, kvhp, qscale);

    k_attn<<<N_NODES, 256, 0, stream>>>(row_ptr, ecol, qhp, kvhp, agg);

    dim3 go((N_NODES + 63) / 64, HIDDEN / 128);
    k_gemm_o<<<go, 256, 0, stream>>>(agg, wo, o_b, out);
}

// Round 14
// 175.251 us; speedup vs baseline: 1.2945x; 1.2945x over previous
//
#include <hip/hip_runtime.h>
#include <hip/hip_bf16.h>

#define N_NODES 20000
#define N_EDGES 640000
#define HIDDEN 256
#define HEADS 8
#define HEAD_DIM 32
#define N_FEATS 9
#define VOCAB 119

typedef __hip_bfloat16 bf16;
typedef __attribute__((ext_vector_type(8))) short short8;
typedef __attribute__((ext_vector_type(4))) float f32x4;

__device__ __forceinline__ ushort f2u(float x) { union { ushort u; bf16 b; } c; c.b = __float2bfloat16(x); return c.u; }
__device__ __forceinline__ void unpack8(uint4 u, float* f) {
    f[0] = __uint_as_float(u.x << 16); f[1] = __uint_as_float(u.x & 0xffff0000u);
    f[2] = __uint_as_float(u.y << 16); f[3] = __uint_as_float(u.y & 0xffff0000u);
    f[4] = __uint_as_float(u.z << 16); f[5] = __uint_as_float(u.z & 0xffff0000u);
    f[6] = __uint_as_float(u.w << 16); f[7] = __uint_as_float(u.w & 0xffff0000u);
}
__device__ __forceinline__ uint pack2(float a, float b) {
    union { __hip_bfloat162 h; uint u; } c;
    c.h = __float22bfloat162_rn(make_float2(a, b));
    return c.u;
}

// 2-way bf16 dot with f32 accumulate: 1 VALU instr, operands already packed.
#if __has_builtin(__builtin_amdgcn_fdot2_f32_bf16)
typedef __attribute__((ext_vector_type(2))) __bf16 bf16x2_t;
__device__ __forceinline__ float dot2bf(uint a, uint b, float c) {
    return __builtin_amdgcn_fdot2_f32_bf16(__builtin_bit_cast(bf16x2_t, a),
                                           __builtin_bit_cast(bf16x2_t, b), c, false);
}
#else
__device__ __forceinline__ float dot2bf(uint a, uint b, float c) {
    return c + __uint_as_float(a << 16) * __uint_as_float(b << 16)
             + __uint_as_float(a & 0xffff0000u) * __uint_as_float(b & 0xffff0000u);
}
#endif

// ---------------------------------------------------------------- fused pre-work
// blocks [0,5000): encode  (h[n][t] = sum_f emb[f][X[n,f]][t], bf16 out)
// blocks [5000,6027): weight fp32->bf16 (concat qkv) + bias concat
// blocks [6027,6106): row_ptr by binary search
__global__ void k_pre(const int* __restrict__ X, const float* __restrict__ emb,
                      bf16* __restrict__ h,
                      const float* __restrict__ qw, const float* __restrict__ kw,
                      const float* __restrict__ vw, const float* __restrict__ ow,
                      const float* __restrict__ qb, const float* __restrict__ kb,
                      const float* __restrict__ vb,
                      bf16* __restrict__ wqkv, bf16* __restrict__ wo,
                      float* __restrict__ qkvb,
                      const int* __restrict__ erow, int* __restrict__ row_ptr) {
    int b = blockIdx.x;
    if (b < 5000) {
        int tid = b * 256 + threadIdx.x;
        int n = tid >> 6;
        int c4 = (tid & 63) * 4;
        float4 a = make_float4(0.f, 0.f, 0.f, 0.f);
#pragma unroll
        for (int f = 0; f < N_FEATS; ++f) {
            int idx = X[n * N_FEATS + f];
            float4 e = *(const float4*)(emb + ((size_t)(f * VOCAB + idx)) * HIDDEN + c4);
            a.x += e.x; a.y += e.y; a.z += e.z; a.w += e.w;
        }
        ushort4 o = make_ushort4(f2u(a.x), f2u(a.y), f2u(a.z), f2u(a.w));
        *(ushort4*)((ushort*)h + (size_t)n * HIDDEN + c4) = o;
    } else if (b < 6027) {
        int i = (b - 5000) * 256 + threadIdx.x;     // 262912 total
        if (i < 196608) {
            const float* s = i < 65536 ? qw : i < 131072 ? kw : vw;
            wqkv[i] = __float2bfloat16(s[i & 65535]);
        } else if (i < 262144) {
            wo[i - 196608] = __float2bfloat16(ow[i - 196608]);
        } else if (i < 262912) {
            int j = i - 262144;                      // 768 bias elems
            const float* s = j < 256 ? qb : j < 512 ? kb : vb;
            qkvb[j] = s[j & 255];
        }
    } else {
        int n = (b - 6027) * 256 + threadIdx.x;
        if (n > N_NODES) return;
        int lo = 0, hi = N_EDGES;
        while (lo < hi) {
            int mid = (lo + hi) >> 1;
            if (erow[mid] < n) lo = mid + 1; else hi = mid;
        }
        row_ptr[n] = lo;
    }
}

// ---------------------------------------------------------------- MFMA GEMM core
// (R10 structure: LDS-staged A+B, register prefetch, 2 barriers/K-iter.)
// MODE 0: qkv -> head-pair-sliced layouts  qhp[hp][n][64], kvhp[hp][n][128]
// MODE 1: float out [n][256]
// GUARD: per-element n bounds checks (only the last x-block needs them)
// TM: row-tile (128 or 64). Cols always 128.
template <int MODE, bool GUARD, int TM>
__device__ __forceinline__ void gemm_core(const bf16* __restrict__ A,
                                          const bf16* __restrict__ W,
                                          const float* __restrict__ bias,
                                          void* __restrict__ Y0, void* __restrict__ Y1,
                                          float s_q, int n0, int d0) {
    constexpr int RI = TM / 32;          // row subtiles per wave (4 or 2)
    __shared__ short As[TM * 72];
    __shared__ short Bs[128 * 72];
    int t = threadIdx.x;
    int lane = t & 63, w = t >> 6;
    int wr = (w >> 1) * (TM / 2), wc = (w & 1) * 64;
    int lr = lane & 15, quad = lane >> 4;

    f32x4 acc[RI][4] = {};
    short8 ra[RI], rb[4];
    int srowA[RI], skoA[RI], srowB[4], skoB[4];
#pragma unroll
    for (int it = 0; it < RI; ++it) { int c = t + 256 * it; srowA[it] = c >> 3; skoA[it] = (c & 7) * 8; }
#pragma unroll
    for (int it = 0; it < 4; ++it) { int c = t + 256 * it; srowB[it] = c >> 3; skoB[it] = (c & 7) * 8; }

    // prologue: load k0=0, stage to LDS
#pragma unroll
    for (int it = 0; it < RI; ++it) {
        int n = n0 + srowA[it];
        short8 av = {};
        if (!GUARD || n < N_NODES) av = *(const short8*)(A + (size_t)n * HIDDEN + skoA[it]);
        ra[it] = av;
    }
#pragma unroll
    for (int it = 0; it < 4; ++it)
        rb[it] = *(const short8*)(W + (size_t)(d0 + srowB[it]) * HIDDEN + skoB[it]);
#pragma unroll
    for (int it = 0; it < RI; ++it) *(short8*)(&As[srowA[it] * 72 + skoA[it]]) = ra[it];
#pragma unroll
    for (int it = 0; it < 4; ++it)  *(short8*)(&Bs[srowB[it] * 72 + skoB[it]]) = rb[it];
    __syncthreads();

    for (int k0 = 64; k0 < 256; k0 += 64) {
        // prefetch next K-slab into regs (overlaps with MFMA below)
#pragma unroll
        for (int it = 0; it < RI; ++it) {
            int n = n0 + srowA[it];
            short8 av = {};
            if (!GUARD || n < N_NODES) av = *(const short8*)(A + (size_t)n * HIDDEN + k0 + skoA[it]);
            ra[it] = av;
        }
#pragma unroll
        for (int it = 0; it < 4; ++it)
            rb[it] = *(const short8*)(W + (size_t)(d0 + srowB[it]) * HIDDEN + k0 + skoB[it]);
        {
            short8 af[RI][2], bfr[4][2];
#pragma unroll
            for (int i = 0; i < RI; ++i)
#pragma unroll
                for (int kk = 0; kk < 2; ++kk)
                    af[i][kk] = *(short8*)(&As[(wr + i * 16 + lr) * 72 + kk * 32 + quad * 8]);
#pragma unroll
            for (int j = 0; j < 4; ++j)
#pragma unroll
                for (int kk = 0; kk < 2; ++kk)
                    bfr[j][kk] = *(short8*)(&Bs[(wc + j * 16 + lr) * 72 + kk * 32 + quad * 8]);
#pragma unroll
            for (int kk = 0; kk < 2; ++kk)
#pragma unroll
                for (int i = 0; i < RI; ++i)
#pragma unroll
                    for (int j = 0; j < 4; ++j)
                        acc[i][j] = __builtin_amdgcn_mfma_f32_16x16x32_bf16(
                            af[i][kk], bfr[j][kk], acc[i][j], 0, 0, 0);
        }
        __syncthreads();
#pragma unroll
        for (int it = 0; it < RI; ++it) *(short8*)(&As[srowA[it] * 72 + skoA[it]]) = ra[it];
#pragma unroll
        for (int it = 0; it < 4; ++it)  *(short8*)(&Bs[srowB[it] * 72 + skoB[it]]) = rb[it];
        __syncthreads();
    }
    // last compute
    {
        short8 af[RI][2], bfr[4][2];
#pragma unroll
        for (int i = 0; i < RI; ++i)
#pragma unroll
            for (int kk = 0; kk < 2; ++kk)
                af[i][kk] = *(short8*)(&As[(wr + i * 16 + lr) * 72 + kk * 32 + quad * 8]);
#pragma unroll
        for (int j = 0; j < 4; ++j)
#pragma unroll
            for (int kk = 0; kk < 2; ++kk)
                bfr[j][kk] = *(short8*)(&Bs[(wc + j * 16 + lr) * 72 + kk * 32 + quad * 8]);
#pragma unroll
        for (int kk = 0; kk < 2; ++kk)
#pragma unroll
            for (int i = 0; i < RI; ++i)
#pragma unroll
                for (int j = 0; j < 4; ++j)
                    acc[i][j] = __builtin_amdgcn_mfma_f32_16x16x32_bf16(
                        af[i][kk], bfr[j][kk], acc[i][j], 0, 0, 0);
    }

    // epilogue: C/D layout col=lane&15, row=quad*4+reg
    // target selection is UNIFORM per j (dbase has no lane term) -> scalar branches
#pragma unroll
    for (int j = 0; j < 4; ++j) {
        int dbase = d0 + wc + j * 16;          // uniform
        float bj = bias[dbase + lr];
        if constexpr (MODE == 0) {
            float sc = (dbase < 256) ? s_q : 1.f;
            ushort* dst; int stride;
            if (dbase < 256) {
                dst = (ushort*)Y0 + (size_t)(dbase >> 6) * N_NODES * 64 + (dbase & 63) + lr;
                stride = 64;
            } else if (dbase < 512) {
                int e = dbase - 256;
                dst = (ushort*)Y1 + (size_t)(e >> 6) * N_NODES * 128 + (e & 63) + lr;
                stride = 128;
            } else {
                int e = dbase - 512;
                dst = (ushort*)Y1 + (size_t)(e >> 6) * N_NODES * 128 + 64 + (e & 63) + lr;
                stride = 128;
            }
#pragma unroll
            for (int i = 0; i < RI; ++i)
#pragma unroll
                for (int r = 0; r < 4; ++r) {
                    int n = n0 + wr + i * 16 + quad * 4 + r;
                    if (GUARD && n >= N_NODES) continue;
                    dst[(size_t)n * stride] = f2u((acc[i][j][r] + bj) * sc);
                }
        } else {
            float* dst = (float*)Y0 + dbase + lr;
#pragma unroll
            for (int i = 0; i < RI; ++i)
#pragma unroll
                for (int r = 0; r < 4; ++r) {
                    int n = n0 + wr + i * 16 + quad * 4 + r;
                    if (GUARD && n >= N_NODES) continue;
                    dst[(size_t)n * HIDDEN] = acc[i][j][r] + bj;
                }
        }
    }
}

__global__ __launch_bounds__(256, 2) void k_gemm_qkv(
    const bf16* __restrict__ A, const bf16* __restrict__ wqkv,
    const float* __restrict__ qkvb, ushort* __restrict__ qhp,
    ushort* __restrict__ kvhp, float qscale) {
    int n0 = blockIdx.x * 128;
    if (n0 + 128 <= N_NODES)
        gemm_core<0, false, 128>(A, wqkv, qkvb, qhp, kvhp, qscale, n0, blockIdx.y * 128);
    else
        gemm_core<0, true, 128>(A, wqkv, qkvb, qhp, kvhp, qscale, n0, blockIdx.y * 128);
}

// TM=64: 626 blocks (2.4/CU), 27 KB LDS, 4 blocks/CU occupancy target
__global__ __launch_bounds__(256, 4) void k_gemm_o(
    const bf16* __restrict__ A, const bf16* __restrict__ W,
    const float* __restrict__ bias, float* __restrict__ Y) {
    int n0 = blockIdx.x * 64;
    if (n0 + 64 <= N_NODES)
        gemm_core<1, false, 64>(A, W, bias, Y, nullptr, 1.f, n0, blockIdx.y * 128);
    else
        gemm_core<1, true, 64>(A, W, bias, Y, nullptr, 1.f, n0, blockIdx.y * 128);
}

// ---------------------------------------------------------------- fused attention
// Head-pair partitioned (XCD-local kv) + zero-waste lanes + packed bf16 dot +
// distance-2 software pipeline with NAMED register buffers (ka/va, kb2/vb2 —
// no dynamically-indexed locals: R13's kbuf[it&1] was demoted to LDS by the
// compiler, 1.1e7 bank-conflict cycles). Manual 2x unroll; odd tails handled
// by the p-mask (wrapped &63 loads always hit valid cols of the same node).
__global__ __launch_bounds__(256) void k_attn(
    const int* __restrict__ row_ptr, const int* __restrict__ col,
    const ushort* __restrict__ qhp, const ushort* __restrict__ kvhp,
    bf16* __restrict__ agg) {
    int b = blockIdx.x;
    int x = b & 7;
    int hp = x & 3;
    int wave = threadIdx.x >> 6;
    int n = (b >> 3) * 8 + (x >> 2) * 4 + wave;
    int lane = threadIdx.x & 63;
    int my = lane >> 3;          // edge slot 0..7
    int d8 = lane & 7;           // dim slot (head = d8>>2)

    int start = row_ptr[n];
    int deg = row_ptr[n + 1] - start;

    ushort* orow = (ushort*)agg + (size_t)n * HIDDEN + hp * 64 + d8 * 8;
    if (deg == 0) {
        if (lane < 8) { uint4 zo = {}; *(uint4*)orow = zo; }
        return;
    }

    const ushort* qrow = qhp + ((size_t)hp * N_NODES + n) * 64;
    uint4 qu = *(const uint4*)(qrow + d8 * 8);   // packed bf16 pairs, no unpack

    const ushort* kvbase = kvhp + (size_t)hp * N_NODES * 128;
    const int* cb = col + start;

    float z = 0.f;
    float av[8] = {};

    if (deg <= 64) {                      // deg ~ Poisson(32): nearly always
        int c_all = cb[min(lane, deg - 1)];
        int nb = (deg + 7) >> 3;          // 1..8 iterations of 8 edges

        // prologue: iters 0 and 1 (wrapped -> always-valid cols)
        int c0 = __shfl(c_all, my);
        int c1 = __shfl(c_all, (8 + my) & 63);
        const ushort* p0 = kvbase + (((uint)c0 << 7) + (uint)d8 * 8);
        const ushort* p1 = kvbase + (((uint)c1 << 7) + (uint)d8 * 8);
        uint4 ka  = *(const uint4*)(p0), va  = *(const uint4*)(p0 + 64);
        uint4 kb2 = *(const uint4*)(p1), vb2 = *(const uint4*)(p1 + 64);

#pragma unroll 1
        for (int it = 0; it < nb; it += 2) {
            // prefetch it+2, it+3 (wrapped)
            int cn0 = __shfl(c_all, ((it + 2) * 8 + my) & 63);
            int cn1 = __shfl(c_all, ((it + 3) * 8 + my) & 63);
            const ushort* pn0 = kvbase + (((uint)cn0 << 7) + (uint)d8 * 8);
            const ushort* pn1 = kvbase + (((uint)cn1 << 7) + (uint)d8 * 8);
            uint4 kn0 = *(const uint4*)(pn0), vn0 = *(const uint4*)(pn0 + 64);
            uint4 kn1 = *(const uint4*)(pn1), vn1 = *(const uint4*)(pn1 + 64);

            // compute iter it on (ka, va)
            {
                float sa = dot2bf(ka.x, qu.x, 0.f);
                float sb = dot2bf(ka.y, qu.y, 0.f);
                sa = dot2bf(ka.z, qu.z, sa);
                sb = dot2bf(ka.w, qu.w, sb);
                float s = sa + sb;
                s += __shfl_xor(s, 1);
                s += __shfl_xor(s, 2);
                float p = (it * 8 + my < deg) ? __expf(s) : 0.f;
                z += p;
                float vf[8];
                unpack8(va, vf);
#pragma unroll
                for (int d = 0; d < 8; ++d) av[d] += p * vf[d];
            }
            // compute iter it+1 on (kb2, vb2)
            {
                float sa = dot2bf(kb2.x, qu.x, 0.f);
                float sb = dot2bf(kb2.y, qu.y, 0.f);
                sa = dot2bf(kb2.z, qu.z, sa);
                sb = dot2bf(kb2.w, qu.w, sb);
                float s = sa + sb;
                s += __shfl_xor(s, 1);
                s += __shfl_xor(s, 2);
                float p = ((it + 1) * 8 + my < deg) ? __expf(s) : 0.f;
                z += p;
                float vf[8];
                unpack8(vb2, vf);
#pragma unroll
                for (int d = 0; d < 8; ++d) av[d] += p * vf[d];
            }
            ka = kn0; va = vn0; kb2 = kn1; vb2 = vn1;
        }
    } else {
        for (int i = 0; i < deg; i += 8) {
            int idx = i + my;
            int cidx = idx < deg ? idx : deg - 1;
            int c = cb[cidx];
            const ushort* kp = kvbase + (((uint)c << 7) + (uint)d8 * 8);
            uint4 ku = *(const uint4*)(kp);
            uint4 vu = *(const uint4*)(kp + 64);
            float s = dot2bf(ku.x, qu.x, 0.f);
            s = dot2bf(ku.y, qu.y, s);
            s = dot2bf(ku.z, qu.z, s);
            s = dot2bf(ku.w, qu.w, s);
            s += __shfl_xor(s, 1);
            s += __shfl_xor(s, 2);
            float p = (idx < deg) ? __expf(s) : 0.f;
            z += p;
            float vf[8];
            unpack8(vu, vf);
#pragma unroll
            for (int d = 0; d < 8; ++d) av[d] += p * vf[d];
        }
    }

    // combine the 8 edge slots: orbits preserve d8 (dims/heads stay separate)
    z += __shfl_xor(z, 8); z += __shfl_xor(z, 16); z += __shfl_xor(z, 32);
#pragma unroll
    for (int d = 0; d < 8; ++d) {
        av[d] += __shfl_xor(av[d], 8);
        av[d] += __shfl_xor(av[d], 16);
        av[d] += __shfl_xor(av[d], 32);
    }

    if (lane < 8) {                      // slot-0 lanes hold the totals
        float invz = 1.f / z;
        uint4 o;
        o.x = pack2(av[0] * invz, av[1] * invz);
        o.y = pack2(av[2] * invz, av[3] * invz);
        o.z = pack2(av[4] * invz, av[5] * invz);
        o.w = pack2(av[6] * invz, av[7] * invz);
        *(uint4*)orow = o;
    }
}

// ---------------------------------------------------------------- launch
extern "C" void kernel_launch(void* const* d_in, const int* in_sizes, int n_in,
                              void* d_out, int out_size, void* d_ws, size_t ws_size,
                              hipStream_t stream) {
    const int*   X    = (const int*)d_in[0];
    const int*   erow = (const int*)d_in[1];
    const int*   ecol = (const int*)d_in[2];
    const float* emb  = (const float*)d_in[3];
    const float* q_w  = (const float*)d_in[4];
    const float* q_b  = (const float*)d_in[5];
    const float* k_w  = (const float*)d_in[6];
    const float* k_b  = (const float*)d_in[7];
    const float* v_w  = (const float*)d_in[8];
    const float* v_b  = (const float*)d_in[9];
    const float* o_w  = (const float*)d_in[10];
    const float* o_b  = (const float*)d_in[11];
    float* out = (float*)d_out;

    char* ws = (char*)d_ws;
    // layout (bytes):
    //   h / agg (aliased) : bf16 N*256       = 10,240,000  @ 0
    //   qhp               : bf16 4*N*64      = 10,240,000  @ 10,240,000
    //   kvhp              : bf16 4*N*128     = 20,480,000  @ 20,480,000
    //   wqkv              : bf16 768*256     =    393,216  @ 40,960,000
    //   wo                : bf16 256*256     =    131,072  @ 41,353,216
    //   qkvb              : fp32 768         =      3,072  @ 41,484,288
    //   row_ptr           : int (N+1)        =     80,004  @ 41,487,360
    bf16*   h    = (bf16*)(ws);
    bf16*   agg  = (bf16*)(ws);                 // aliases h (dead after QKV GEMM)
    ushort* qhp  = (ushort*)(ws + 10240000);
    ushort* kvhp = (ushort*)(ws + 20480000);
    bf16*   wqkv = (bf16*)(ws + 40960000);
    bf16*   wo   = (bf16*)(ws + 41353216);
    float*  qkvb = (float*)(ws + 41484288);
    int* row_ptr = (int*)(ws + 41487360);

    // fused pre-work: encode (5000) + weight prep (1027) + row_ptr (79)
    k_pre<<<6106, 256, 0, stream>>>(X, emb, h, q_w, k_w, v_w, o_w,
                                    q_b, k_b, v_b, wqkv, wo, qkvb, erow, row_ptr);

    const float qscale = 0.17677669529663687f;  // 1/sqrt(32)
    dim3 gqkv((N_NODES + 127) / 128, 768 / 128);
    k_gemm_qkv<<<gqkv, 256, 0, stream>>>(h, wqkv, qkvb, qhp, kvhp, qscale);

    k_attn<<<N_NODES, 256, 0, stream>>>(row_ptr, ecol, qhp, kvhp, agg);

    dim3 go((N_NODES + 63) / 64, HIDDEN / 128);
    k_gemm_o<<<go, 256, 0, stream>>>(agg, wo, o_b, out);
}